// Round 13
// baseline (795.058 us; speedup 1.0000x reference)
//
#include <hip/hip_runtime.h>

// AttnBlock2D: GroupNorm -> fused QKV -> 1-head attention (hw=4096, dh=512) -> proj + residual
// R13 = R12 (663us) + PV moved to a 256x128 BK=64 depth-2 counted-vmcnt engine (gemm_pvw):
//       512 thr / 8 waves (4Mx2N, 64x64/wave), LDS 96KB, grid exactly 256 blocks/slice
//       (1 block/CU, one round), staged bytes -25% at unchanged barrier cadence.
//       QKV/S/res engines untouched for clean attribution.

#define BATCH 8
#define CCH 512
#define HWP 4096
#define NG 32

#define AS1 __attribute__((address_space(1)))
#define AS3 __attribute__((address_space(3)))

typedef __attribute__((ext_vector_type(8))) short s16x8;
typedef __attribute__((ext_vector_type(4))) float f32x4;

__device__ __forceinline__ unsigned short f2bf(float f) {
  union { float f; unsigned u; } v; v.f = f;
  return (unsigned short)((v.u + 0x7FFFu + ((v.u >> 16) & 1u)) >> 16);
}

// ---------------- weight convert f32 -> bf16 (4 matrices) + qkv bias concat ----------------
__global__ void cvt_w(const float* __restrict__ w0, const float* __restrict__ w1,
                      const float* __restrict__ w2, const float* __restrict__ w3,
                      const float* __restrict__ bq, const float* __restrict__ bk,
                      const float* __restrict__ bv,
                      unsigned short* __restrict__ out, float* __restrict__ bcat) {
  int i = blockIdx.x * 256 + threadIdx.x;
  const int n = CCH * CCH;
  if (i < CCH) {
    bcat[i]           = bq[i];
    bcat[CCH + i]     = bk[i];
    bcat[2 * CCH + i] = bv[i];
  }
  if (i < n) {
    out[i]         = f2bf(w0[i]);
    out[n + i]     = f2bf(w1[i]);
    out[2 * n + i] = f2bf(w2[i]);
    out[3 * n + i] = f2bf(w3[i]);
  }
}

// ---------------- GroupNorm stats: one block per (b,g) ----------------
__global__ void gn_stats(const float* __restrict__ x, float* __restrict__ stats) {
  const int bg = blockIdx.x;
  const float* base = x + (size_t)bg * (16 * HWP);
  float s = 0.f, sq = 0.f;
  for (int i = threadIdx.x; i < 16 * HWP / 4; i += 256) {
    float4 v = ((const float4*)base)[i];
    s += v.x + v.y + v.z + v.w;
    sq += v.x * v.x + v.y * v.y + v.z * v.z + v.w * v.w;
  }
  #pragma unroll
  for (int o = 32; o; o >>= 1) { s += __shfl_xor(s, o); sq += __shfl_xor(sq, o); }
  __shared__ float ls[4], lq[4];
  const int wv = threadIdx.x >> 6;
  if ((threadIdx.x & 63) == 0) { ls[wv] = s; lq[wv] = sq; }
  __syncthreads();
  if (threadIdx.x == 0) {
    s = ls[0] + ls[1] + ls[2] + ls[3];
    sq = lq[0] + lq[1] + lq[2] + lq[3];
    const float inv_n = 1.f / (16.f * HWP);
    float mean = s * inv_n;
    float var = sq * inv_n - mean * mean;
    stats[2 * bg] = mean;
    stats[2 * bg + 1] = rsqrtf(var + 1e-5f);
  }
}

// ---------------- GroupNorm apply + transpose -> h_t (hw, c) bf16 ----------------
__global__ void gn_apply(const float* __restrict__ x, const float* __restrict__ stats,
                         const float* __restrict__ scale, const float* __restrict__ bias,
                         unsigned short* __restrict__ ht) {
  const int p0 = blockIdx.x * 64, c0 = blockIdx.y * 64, b = blockIdx.z;
  const int tx = threadIdx.x & 63, ty = threadIdx.x >> 6;
  __shared__ unsigned short tile[64][65];
  #pragma unroll 4
  for (int j = 0; j < 16; ++j) {
    int cl = ty + j * 4;
    int c = c0 + cl;
    int g = c >> 4;
    float mean = stats[(b * NG + g) * 2];
    float rstd = stats[(b * NG + g) * 2 + 1];
    float v = x[((size_t)(b * CCH + c)) * HWP + p0 + tx];
    v = (v - mean) * rstd * scale[c] + bias[c];
    tile[cl][tx] = f2bf(v);
  }
  __syncthreads();
  #pragma unroll 4
  for (int j = 0; j < 16; ++j) {
    int pl = ty + j * 4;
    ht[((size_t)b * HWP + p0 + pl) * CCH + c0 + tx] = tile[tx][pl];
  }
}

// ---------------- NT GEMM (R3 engine): 128x128, BK=64, dbuf ----------------
// MODE 0: bf16 out + biasCol; if Res!=null and n0>=1024, tile is V: transpose via LDS
//         bounce (pad 152) and write to vT (=Res, stride sRes).  (fused QKV+V^T)
// MODE 3: f32 out, + biasRow + Res(prefetched to regs), coalesced epilogue (final proj)
template<int MODE>
__device__ __forceinline__ void gemm_body(
    const unsigned short* __restrict__ A, const unsigned short* __restrict__ Bm,
    void* __restrict__ Cm, const float* __restrict__ biasRow,
    const float* __restrict__ biasCol, const float* __restrict__ Res,
    int K, int lda, int ldb, int ldc, float scale,
    long long sA, long long sB, long long sC, long long sRes) {
  const int nbx = gridDim.x, nby = gridDim.y;
  const int nb = nbx * nby * gridDim.z;
  int lin = (blockIdx.z * nby + blockIdx.y) * nbx + blockIdx.x;
  int bx, by, bz;
  if ((nb & 7) == 0) {
    int logical = (lin & 7) * (nb >> 3) + (lin >> 3);
    bx = logical % nbx;
    int t = logical / nbx;
    by = t % nby;
    bz = t / nby;
  } else { bx = blockIdx.x; by = blockIdx.y; bz = blockIdx.z; }

  const unsigned short* Ab = A + (size_t)bz * sA;
  const unsigned short* Bb = Bm + (size_t)bz * sB;
  const int m0 = by * 128, n0 = bx * 128;
  __shared__ __align__(16) unsigned short sm[2][2][128 * 64];
  const int tid = threadIdx.x, wave = tid >> 6, lane = tid & 63;
  const int wr = (wave >> 1) * 64, wc = (wave & 1) * 64;
  const int lr = lane & 15, lkc = lane >> 4;
  f32x4 acc[4][4] = {};

  float4 xr[16];
  if (MODE == 3) {
    #pragma unroll
    for (int pass = 0; pass < 2; ++pass)
      #pragma unroll
      for (int i = 0; i < 8; ++i) {
        int idx = i * 256 + tid;
        int rrow = idx >> 5, c4 = (idx & 31) << 2;
        size_t gidx = (size_t)(m0 + pass * 64 + rrow) * ldc + (n0 + c4);
        xr[pass * 8 + i] = *(const float4*)&Res[(size_t)bz * sRes + gidx];
      }
  }

  const int chunkBase = wave * 64 + lane;
  int srow[4], sc8[4];
  #pragma unroll
  for (int it = 0; it < 4; ++it) {
    int chunk = it * 256 + chunkBase;
    srow[it] = chunk >> 3;
    sc8[it] = (((chunk & 7) ^ (srow[it] & 7)) * 8);
  }

  #define STAGE(buf, kt)                                                                 \
    { _Pragma("unroll")                                                                  \
      for (int it = 0; it < 4; ++it) {                                                   \
        __builtin_amdgcn_global_load_lds(                                                \
            (const AS1 unsigned int*)(Ab + (size_t)(m0 + srow[it]) * lda + (kt) + sc8[it]), \
            (AS3 unsigned int*)(&sm[0][buf][0] + (size_t)(it * 256 + wave * 64) * 8), 16, 0, 0); \
        __builtin_amdgcn_global_load_lds(                                                \
            (const AS1 unsigned int*)(Bb + (size_t)(n0 + srow[it]) * ldb + (kt) + sc8[it]), \
            (AS3 unsigned int*)(&sm[1][buf][0] + (size_t)(it * 256 + wave * 64) * 8), 16, 0, 0); \
      }                                                                                  \
    }

  STAGE(0, 0);
  __syncthreads();
  int cur = 0;
  for (int kt = 0; kt < K; kt += 64) {
    if (kt + 64 < K) STAGE(cur ^ 1, kt + 64);
    #pragma unroll
    for (int kk = 0; kk < 64; kk += 32) {
      const int jbase = (kk >> 3) + lkc;
      s16x8 af[4], bfv[4];
      #pragma unroll
      for (int m = 0; m < 4; ++m) {
        int r = wr + m * 16 + lr;
        af[m] = *(const s16x8*)&sm[0][cur][r * 64 + ((jbase ^ (r & 7)) << 3)];
      }
      #pragma unroll
      for (int n = 0; n < 4; ++n) {
        int r = wc + n * 16 + lr;
        bfv[n] = *(const s16x8*)&sm[1][cur][r * 64 + ((jbase ^ (r & 7)) << 3)];
      }
      #pragma unroll
      for (int m = 0; m < 4; ++m)
        #pragma unroll
        for (int n = 0; n < 4; ++n)
          acc[m][n] = __builtin_amdgcn_mfma_f32_16x16x32_bf16(af[m], bfv[n], acc[m][n], 0, 0, 0);
    }
    __syncthreads();
    cur ^= 1;
  }
  #undef STAGE

  const int r0 = (lane >> 4) * 4, ccol = lane & 15;
  if (MODE == 0 && Res != nullptr && n0 >= 1024) {
    unsigned short* lt = (unsigned short*)&sm[0][0][0];   // [128][152] bf16
    #pragma unroll
    for (int m = 0; m < 4; ++m) {
      const int gm_l = wr + m * 16 + r0;
      #pragma unroll
      for (int n = 0; n < 4; ++n) {
        const int gn_l = wc + n * 16 + ccol;
        const float bc = biasCol ? biasCol[n0 + gn_l] : 0.f;
        union { unsigned short us[4]; uint2 u2; } pk;
        #pragma unroll
        for (int r = 0; r < 4; ++r) pk.us[r] = f2bf(acc[m][n][r] + bc);
        *(uint2*)&lt[gn_l * 152 + gm_l] = pk.u2;
      }
    }
    __syncthreads();
    unsigned short* vout = (unsigned short*)Res;
    const int c0v = n0 - 1024;
    #pragma unroll
    for (int i = 0; i < 8; ++i) {
      int idx = i * 256 + tid;
      int orow = idx >> 4, pc = (idx & 15) * 8;
      s16x8 v = *(const s16x8*)&lt[orow * 152 + pc];
      *(s16x8*)&vout[(size_t)bz * sRes + (size_t)(c0v + orow) * HWP + m0 + pc] = v;
    }
  } else if (MODE != 3) {
    #pragma unroll
    for (int m = 0; m < 4; ++m) {
      const int gm = m0 + wr + m * 16 + r0;
      #pragma unroll
      for (int n = 0; n < 4; ++n) {
        const int gn = n0 + wc + n * 16 + ccol;
        const float bc = biasCol ? biasCol[gn] : 0.f;
        #pragma unroll
        for (int r = 0; r < 4; ++r) {
          float val = acc[m][n][r] * scale + bc;
          size_t idx = (size_t)(gm + r) * ldc + gn;
          ((unsigned short*)Cm)[(size_t)bz * sC + idx] = f2bf(val);
        }
      }
    }
  } else {
    float* ft = (float*)&sm[0][0][0];
    float* Cf = (float*)Cm;
    #pragma unroll
    for (int pass = 0; pass < 2; ++pass) {
      __syncthreads();
      if ((wave >> 1) == pass) {
        #pragma unroll
        for (int m = 0; m < 4; ++m) {
          const int rl0 = m * 16 + (lane >> 4) * 4;
          #pragma unroll
          for (int n = 0; n < 4; ++n) {
            const int cl = wc + n * 16 + (lane & 15);
            #pragma unroll
            for (int r = 0; r < 4; ++r) {
              float val = acc[m][n][r];
              if (biasRow) val += biasRow[m0 + pass * 64 + rl0 + r];
              ft[(rl0 + r) * 132 + cl] = val;
            }
          }
        }
      }
      __syncthreads();
      #pragma unroll
      for (int i = 0; i < 8; ++i) {
        int idx = i * 256 + tid;
        int rrow = idx >> 5, c4 = (idx & 31) << 2;
        float4 v = *(const float4*)&ft[rrow * 132 + c4];
        const float4 rv = xr[pass * 8 + i];
        v.x += rv.x; v.y += rv.y; v.z += rv.z; v.w += rv.w;
        size_t gidx = (size_t)(m0 + pass * 64 + rrow) * ldc + (n0 + c4);
        *(float4*)&Cf[(size_t)bz * sC + gidx] = v;
      }
    }
  }
}

#define GEMM_ARGS const unsigned short* A, const unsigned short* Bm, void* Cm,            \
                  const float* biasRow, const float* biasCol, const float* Res,            \
                  int K, int lda, int ldb, int ldc, float scale,                           \
                  long long sA, long long sB, long long sC, long long sRes
#define GEMM_PASS A, Bm, Cm, biasRow, biasCol, Res, K, lda, ldb, ldc, scale, sA, sB, sC, sRes

__global__ __launch_bounds__(256) void gemm_qkv(GEMM_ARGS) { gemm_body<0>(GEMM_PASS); }
__global__ __launch_bounds__(256) void gemm_res(GEMM_ARGS) { gemm_body<3>(GEMM_PASS); }

// ================= S-GEMM: 256x128-tile, BK=32, dbuf, 8 waves, exp epilogue =================
__global__ __launch_bounds__(512)
void gemm_s256(const unsigned short* __restrict__ A, const unsigned short* __restrict__ Bm,
               unsigned short* __restrict__ C,
               int K, int lda, int ldb, int ldc, float scale,
               long long sA, long long sB, long long sC) {
  const int nbx = gridDim.x, nby = gridDim.y;
  const int nb = nbx * nby * gridDim.z;
  int lin = (blockIdx.z * nby + blockIdx.y) * nbx + blockIdx.x;
  int bx, by, bz;
  if ((nb & 7) == 0) {
    int logical = (lin & 7) * (nb >> 3) + (lin >> 3);
    bx = logical % nbx;
    int t = logical / nbx;
    by = t % nby;
    bz = t / nby;
  } else { bx = blockIdx.x; by = blockIdx.y; bz = blockIdx.z; }

  const unsigned short* __restrict__ Ab = A + (size_t)bz * sA;
  const unsigned short* __restrict__ Bb = Bm + (size_t)bz * sB;
  unsigned short* __restrict__ Cb = C + (size_t)bz * sC;
  const int m0 = by * 256, n0 = bx * 128;

  __shared__ __align__(16) unsigned short smA[2][256 * 32];
  __shared__ __align__(16) unsigned short smB[2][128 * 32];

  const int tid = threadIdx.x, wave = tid >> 6, lane = tid & 63;
  const int wr = (wave >> 1) * 64;
  const int wc = (wave & 1) * 64;
  const int lr = lane & 15, lkc = lane >> 4;
  f32x4 acc[4][4] = {};

  int aRow[2], aCol[2];
  #pragma unroll
  for (int it = 0; it < 2; ++it) {
    int chunk = it * 512 + tid;
    int row = chunk >> 2, cc = chunk & 3;
    aRow[it] = row;
    aCol[it] = ((cc ^ ((row >> 1) & 3)) * 8);
  }
  const int bRow = tid >> 2;
  const int bCol = (((tid & 3) ^ ((bRow >> 1) & 3)) * 8);

  #define STG_S(buf, kt)                                                                      \
    { _Pragma("unroll")                                                                       \
      for (int it = 0; it < 2; ++it)                                                          \
        __builtin_amdgcn_global_load_lds(                                                     \
            (const AS1 unsigned int*)(Ab + (size_t)(m0 + aRow[it]) * lda + (kt) + aCol[it]),  \
            (AS3 unsigned int*)(&smA[buf][0] + (size_t)(it * 512 + tid) * 8), 16, 0, 0);      \
      __builtin_amdgcn_global_load_lds(                                                       \
          (const AS1 unsigned int*)(Bb + (size_t)(n0 + bRow) * ldb + (kt) + bCol),            \
          (AS3 unsigned int*)(&smB[buf][0] + (size_t)tid * 8), 16, 0, 0);                     \
    }

  STG_S(0, 0);
  __syncthreads();
  int cur = 0;
  for (int kt = 0; kt < K; kt += 32) {
    if (kt + 32 < K) STG_S(cur ^ 1, kt + 32);
    s16x8 af[4], bfv[4];
    #pragma unroll
    for (int m = 0; m < 4; ++m) {
      int r = wr + m * 16 + lr;
      af[m] = *(const s16x8*)&smA[cur][r * 32 + ((lkc ^ ((r >> 1) & 3)) << 3)];
    }
    #pragma unroll
    for (int n = 0; n < 4; ++n) {
      int rb = wc + n * 16 + lr;
      bfv[n] = *(const s16x8*)&smB[cur][rb * 32 + ((lkc ^ ((rb >> 1) & 3)) << 3)];
    }
    #pragma unroll
    for (int m = 0; m < 4; ++m)
      #pragma unroll
      for (int n = 0; n < 4; ++n)
        acc[m][n] = __builtin_amdgcn_mfma_f32_16x16x32_bf16(af[m], bfv[n], acc[m][n], 0, 0, 0);
    __syncthreads();
    cur ^= 1;
  }
  #undef STG_S

  const int r0 = (lane >> 4) * 4, ccol = lane & 15;
  #pragma unroll
  for (int m = 0; m < 4; ++m) {
    const int gm = m0 + wr + m * 16 + r0;
    #pragma unroll
    for (int n = 0; n < 4; ++n) {
      const int gn = n0 + wc + n * 16 + ccol;
      #pragma unroll
      for (int r = 0; r < 4; ++r) {
        float val = __expf(acc[m][n][r] * scale);
        Cb[(size_t)(gm + r) * ldc + gn] = f2bf(val);
      }
    }
  }
}

// ================= PV wide: 256x128-tile, BK=64, depth-2 counted vmcnt =================
// 512 thr / 8 waves (4M x 2N -> 64x64/wave, acc[4][4] + ones-MFMA denominator).
// LDS 96KB (1 block/CU); grid exactly (4,16,G) = 256 blocks/slice = one full round.
// Stage tile t+2 after the barrier freeing buf t&1; vmcnt(6) = next tile's 6 loads
// stay in flight (never 0 mid-loop). O = (expS . vT^T) / rowsum(expS).
__global__ __launch_bounds__(512)
void gemm_pvw(const unsigned short* __restrict__ A, const unsigned short* __restrict__ Bm,
              unsigned short* __restrict__ C,
              int K, int lda, int ldb, int ldc,
              long long sA, long long sB, long long sC) {
  const int nbx = gridDim.x, nby = gridDim.y;
  const int nb = nbx * nby * gridDim.z;
  int lin = (blockIdx.z * nby + blockIdx.y) * nbx + blockIdx.x;
  int bx, by, bz;
  if ((nb & 7) == 0) {
    int logical = (lin & 7) * (nb >> 3) + (lin >> 3);
    bx = logical % nbx;
    int t = logical / nbx;
    by = t % nby;
    bz = t / nby;
  } else { bx = blockIdx.x; by = blockIdx.y; bz = blockIdx.z; }

  const unsigned short* __restrict__ Ab = A + (size_t)bz * sA;
  const unsigned short* __restrict__ Bb = Bm + (size_t)bz * sB;
  unsigned short* __restrict__ Cb = C + (size_t)bz * sC;
  const int m0 = by * 256, n0 = bx * 128;

  __shared__ __align__(16) unsigned short lsA[2][256 * 64];   // 64 KB
  __shared__ __align__(16) unsigned short lsB[2][128 * 64];   // 32 KB

  const int tid = threadIdx.x, wave = tid >> 6, lane = tid & 63;
  const int wr = (wave >> 1) * 64;                  // 4 M-groups of 64
  const int wc = (wave & 1) * 64;                   // 2 N-groups of 64
  const int lr = lane & 15, lkc = lane >> 4;
  f32x4 acc[4][4] = {};
  f32x4 acc_d[4] = {};
  s16x8 bones;
  #pragma unroll
  for (int j = 0; j < 8; ++j) bones[j] = (short)0x3F80;  // bf16 1.0

  int aRow[4], aCol[4];
  #pragma unroll
  for (int it = 0; it < 4; ++it) {
    int c = it * 512 + tid;
    int row = c >> 3;
    aRow[it] = row;
    aCol[it] = ((c & 7) ^ (row & 7)) * 8;
  }
  int bRow[2], bCol[2];
  #pragma unroll
  for (int it = 0; it < 2; ++it) {
    int c = it * 512 + tid;
    int row = c >> 3;
    bRow[it] = row;
    bCol[it] = ((c & 7) ^ (row & 7)) * 8;
  }

  #define STG_W(buf, kt)                                                                     \
    { _Pragma("unroll")                                                                      \
      for (int it = 0; it < 4; ++it)                                                         \
        __builtin_amdgcn_global_load_lds(                                                    \
            (const AS1 unsigned int*)(Ab + (size_t)(m0 + aRow[it]) * lda + (kt) + aCol[it]), \
            (AS3 unsigned int*)(&lsA[buf][0] + (size_t)(it * 512 + tid) * 8), 16, 0, 0);     \
      _Pragma("unroll")                                                                      \
      for (int it = 0; it < 2; ++it)                                                         \
        __builtin_amdgcn_global_load_lds(                                                    \
            (const AS1 unsigned int*)(Bb + (size_t)(n0 + bRow[it]) * ldb + (kt) + bCol[it]), \
            (AS3 unsigned int*)(&lsB[buf][0] + (size_t)(it * 512 + tid) * 8), 16, 0, 0);     \
    }

  const int nkt = K >> 6;                           // 64 for K=4096
  STG_W(0, 0);
  STG_W(1, 64);
  asm volatile("s_waitcnt vmcnt(6)" ::: "memory");  // tile 0 landed; tile 1 in flight
  __builtin_amdgcn_sched_barrier(0);
  __builtin_amdgcn_s_barrier();
  __builtin_amdgcn_sched_barrier(0);

  for (int t = 0; t < nkt; ++t) {
    const int cur = t & 1;
    const unsigned short* __restrict__ pA = &lsA[cur][0];
    const unsigned short* __restrict__ pB = &lsB[cur][0];
    #pragma unroll
    for (int kk = 0; kk < 64; kk += 32) {
      const int jb = (kk >> 3) + lkc;
      s16x8 af[4], bfv[4];
      #pragma unroll
      for (int m = 0; m < 4; ++m) {
        int r = wr + m * 16 + lr;
        af[m] = *(const s16x8*)&pA[r * 64 + ((jb ^ (r & 7)) << 3)];
      }
      #pragma unroll
      for (int n = 0; n < 4; ++n) {
        int rb = wc + n * 16 + lr;
        bfv[n] = *(const s16x8*)&pB[rb * 64 + ((jb ^ (rb & 7)) << 3)];
      }
      __builtin_amdgcn_s_setprio(1);
      #pragma unroll
      for (int m = 0; m < 4; ++m) {
        #pragma unroll
        for (int n = 0; n < 4; ++n)
          acc[m][n] = __builtin_amdgcn_mfma_f32_16x16x32_bf16(af[m], bfv[n], acc[m][n], 0, 0, 0);
        acc_d[m] = __builtin_amdgcn_mfma_f32_16x16x32_bf16(af[m], bones, acc_d[m], 0, 0, 0);
      }
      __builtin_amdgcn_s_setprio(0);
    }
    if (t == nkt - 1) break;
    __builtin_amdgcn_sched_barrier(0);
    __builtin_amdgcn_s_barrier();                   // all reads of buf cur done
    __builtin_amdgcn_sched_barrier(0);
    if (t + 2 < nkt) {
      STG_W(cur, (t + 2) * 64);
      asm volatile("s_waitcnt vmcnt(6)" ::: "memory");   // tile t+1 landed (never 0)
    } else {
      asm volatile("s_waitcnt vmcnt(0)" ::: "memory");
    }
    __builtin_amdgcn_sched_barrier(0);
    __builtin_amdgcn_s_barrier();
    __builtin_amdgcn_sched_barrier(0);
  }
  #undef STG_W

  const int r0 = (lane >> 4) * 4, ccol = lane & 15;
  #pragma unroll
  for (int m = 0; m < 4; ++m) {
    const int gm = m0 + wr + m * 16 + r0;
    const float inv0 = 1.f / acc_d[m][0];
    const float inv1 = 1.f / acc_d[m][1];
    const float inv2 = 1.f / acc_d[m][2];
    const float inv3 = 1.f / acc_d[m][3];
    #pragma unroll
    for (int n = 0; n < 4; ++n) {
      const int gn = n0 + wc + n * 16 + ccol;
      #pragma unroll
      for (int r = 0; r < 4; ++r) {
        float val = acc[m][n][r] * (r == 0 ? inv0 : r == 1 ? inv1 : r == 2 ? inv2 : inv3);
        Cb[(size_t)(gm + r) * ldc + gn] = f2bf(val);
      }
    }
  }
}

extern "C" void kernel_launch(void* const* d_in, const int* in_sizes, int n_in,
                              void* d_out, int out_size, void* d_ws, size_t ws_size,
                              hipStream_t stream) {
  (void)in_sizes; (void)n_in; (void)out_size;
  const float* x   = (const float*)d_in[0];
  const float* nsc = (const float*)d_in[1];
  const float* nbi = (const float*)d_in[2];
  const float* wq  = (const float*)d_in[3];
  const float* bq  = (const float*)d_in[4];
  const float* wk  = (const float*)d_in[5];
  const float* bk  = (const float*)d_in[6];
  const float* wv  = (const float*)d_in[7];
  const float* bv  = (const float*)d_in[8];
  const float* wp  = (const float*)d_in[9];
  const float* bp  = (const float*)d_in[10];
  float* out = (float*)d_out;
  char* ws = (char*)d_ws;

  const size_t nW = (size_t)CCH * CCH;
  unsigned short* wb = (unsigned short*)ws;            // 2 MB
  float* bcat = (float*)(ws + 4 * nW * 2);             // 6 KB
  float* stats = bcat + 1536;                          // 2 KB
  const size_t o_h = 4 * nW * 2 + 16384;
  unsigned short* ht  = (unsigned short*)(ws + o_h);   // 32 MB  (b, p, 512)
  unsigned short* qkv = ht + (size_t)BATCH * HWP * CCH;        // 96 MB (b, p, 1536)
  unsigned short* vT  = qkv + (size_t)BATCH * HWP * 1536;      // 32 MB (b, c, p)
  unsigned short* Sb  = vT + (size_t)BATCH * CCH * HWP;        // G*32 MB slice (reused)
  unsigned short* ot  = ht;                            // alias: ht dead after QKV gemm
  const size_t o_S = o_h + ((size_t)BATCH * HWP * (CCH + 1536 + CCH)) * 2;
  const size_t sS1b = (size_t)HWP * HWP * 2;
  int G = 4;
  while (G > 1 && o_S + (size_t)G * sS1b > ws_size) G >>= 1;

  const long long sHC  = (long long)HWP * CCH;
  const long long sQKV = (long long)HWP * 1536;
  const long long sS1  = (long long)HWP * HWP;

  cvt_w<<<dim3((unsigned)((nW + 255) / 256)), dim3(256), 0, stream>>>(
      wq, wk, wv, wp, bq, bk, bv, wb, bcat);
  gn_stats<<<dim3(BATCH * NG), dim3(256), 0, stream>>>(x, stats);
  gn_apply<<<dim3(HWP / 64, CCH / 64, BATCH), dim3(256), 0, stream>>>(x, stats, nsc, nbi, ht);

  // fused QKV: qkv[p][o] = sum_c h_t[p][c] wqkv[o][c] + bcat[o];
  // V column-blocks (o>=1024) written TRANSPOSED into vT
  gemm_qkv<<<dim3(1536 / 128, HWP / 128, BATCH), dim3(256), 0, stream>>>(
      ht, wb, qkv, nullptr, bcat, (const float*)vT,
      CCH, CCH, CCH, 1536, 1.f, sHC, 0, sQKV, sHC);

  const float sc = 0.04419417382415922f;               // 512^-0.5
  for (int b0 = 0; b0 < BATCH; b0 += G) {
    // expS[d][e] = exp(sc * sum_c q[d][c] k[e][c])
    gemm_s256<<<dim3(HWP / 128, HWP / 256, G), dim3(512), 0, stream>>>(
        qkv + (size_t)b0 * sQKV, qkv + 512 + (size_t)b0 * sQKV, Sb,
        CCH, 1536, 1536, HWP, sc, sQKV, sQKV, sS1);
    // o_t[d][c] = (sum_e expS[d][e] vT[c][e]) / (sum_e expS[d][e])   (wide engine)
    gemm_pvw<<<dim3(CCH / 128, HWP / 256, G), dim3(512), 0, stream>>>(
        Sb, vT + (size_t)b0 * sHC, ot + (size_t)b0 * sHC,
        HWP, HWP, HWP, CCH, sS1, sHC, sHC);
  }

  // final: out[o][p] = x[o][p] + bp[o] + sum_c wp[o][c] o_t[p][c]   (f32, x prefetched)
  gemm_res<<<dim3(HWP / 128, CCH / 128, BATCH), dim3(256), 0, stream>>>(
      wb + 3 * nW, ot, out, bp, nullptr, x,
      CCH, CCH, CCH, HWP, 1.f, 0, sHC, sHC, sHC);
}

// Round 14
// 660.897 us; speedup vs baseline: 1.2030x; 1.2030x over previous
//
#include <hip/hip_runtime.h>

// AttnBlock2D: GroupNorm -> fused QKV -> 1-head attention (hw=4096, dh=512) -> proj + residual
// R14 = R12 verbatim (measured session-best 663us). R13's wide-PV experiment regressed
//       (1 block/CU cannot cover pipeline drains) and is reverted.
// Banked wins: fused softmax (exp in S epilogue + ones-MFMA denominator in PV),
// V-transpose fused into QKV epilogue, residual register-prefetch in gemm_res,
// bijective XCD swizzle + both-sides LDS XOR swizzle everywhere.

#define BATCH 8
#define CCH 512
#define HWP 4096
#define NG 32

#define AS1 __attribute__((address_space(1)))
#define AS3 __attribute__((address_space(3)))

typedef __attribute__((ext_vector_type(8))) short s16x8;
typedef __attribute__((ext_vector_type(4))) float f32x4;

__device__ __forceinline__ unsigned short f2bf(float f) {
  union { float f; unsigned u; } v; v.f = f;
  return (unsigned short)((v.u + 0x7FFFu + ((v.u >> 16) & 1u)) >> 16);
}

// ---------------- weight convert f32 -> bf16 (4 matrices) + qkv bias concat ----------------
__global__ void cvt_w(const float* __restrict__ w0, const float* __restrict__ w1,
                      const float* __restrict__ w2, const float* __restrict__ w3,
                      const float* __restrict__ bq, const float* __restrict__ bk,
                      const float* __restrict__ bv,
                      unsigned short* __restrict__ out, float* __restrict__ bcat) {
  int i = blockIdx.x * 256 + threadIdx.x;
  const int n = CCH * CCH;
  if (i < CCH) {
    bcat[i]           = bq[i];
    bcat[CCH + i]     = bk[i];
    bcat[2 * CCH + i] = bv[i];
  }
  if (i < n) {
    out[i]         = f2bf(w0[i]);
    out[n + i]     = f2bf(w1[i]);
    out[2 * n + i] = f2bf(w2[i]);
    out[3 * n + i] = f2bf(w3[i]);
  }
}

// ---------------- GroupNorm stats: one block per (b,g) ----------------
__global__ void gn_stats(const float* __restrict__ x, float* __restrict__ stats) {
  const int bg = blockIdx.x;
  const float* base = x + (size_t)bg * (16 * HWP);
  float s = 0.f, sq = 0.f;
  for (int i = threadIdx.x; i < 16 * HWP / 4; i += 256) {
    float4 v = ((const float4*)base)[i];
    s += v.x + v.y + v.z + v.w;
    sq += v.x * v.x + v.y * v.y + v.z * v.z + v.w * v.w;
  }
  #pragma unroll
  for (int o = 32; o; o >>= 1) { s += __shfl_xor(s, o); sq += __shfl_xor(sq, o); }
  __shared__ float ls[4], lq[4];
  const int wv = threadIdx.x >> 6;
  if ((threadIdx.x & 63) == 0) { ls[wv] = s; lq[wv] = sq; }
  __syncthreads();
  if (threadIdx.x == 0) {
    s = ls[0] + ls[1] + ls[2] + ls[3];
    sq = lq[0] + lq[1] + lq[2] + lq[3];
    const float inv_n = 1.f / (16.f * HWP);
    float mean = s * inv_n;
    float var = sq * inv_n - mean * mean;
    stats[2 * bg] = mean;
    stats[2 * bg + 1] = rsqrtf(var + 1e-5f);
  }
}

// ---------------- GroupNorm apply + transpose -> h_t (hw, c) bf16 ----------------
__global__ void gn_apply(const float* __restrict__ x, const float* __restrict__ stats,
                         const float* __restrict__ scale, const float* __restrict__ bias,
                         unsigned short* __restrict__ ht) {
  const int p0 = blockIdx.x * 64, c0 = blockIdx.y * 64, b = blockIdx.z;
  const int tx = threadIdx.x & 63, ty = threadIdx.x >> 6;
  __shared__ unsigned short tile[64][65];
  #pragma unroll 4
  for (int j = 0; j < 16; ++j) {
    int cl = ty + j * 4;
    int c = c0 + cl;
    int g = c >> 4;
    float mean = stats[(b * NG + g) * 2];
    float rstd = stats[(b * NG + g) * 2 + 1];
    float v = x[((size_t)(b * CCH + c)) * HWP + p0 + tx];
    v = (v - mean) * rstd * scale[c] + bias[c];
    tile[cl][tx] = f2bf(v);
  }
  __syncthreads();
  #pragma unroll 4
  for (int j = 0; j < 16; ++j) {
    int pl = ty + j * 4;
    ht[((size_t)b * HWP + p0 + pl) * CCH + c0 + tx] = tile[tx][pl];
  }
}

// ---------------- NT GEMM (R3 engine): C = scale*A[M,K]*B[N,K]^T, 128x128, BK=64, dbuf ----------------
// MODE 0: bf16 out + biasCol; if Res!=null and n0>=1024, tile is V: transpose via LDS
//         bounce (pad 152) and write to vT (=Res, stride sRes).  (fused QKV+V^T)
// MODE 2: bf16 out, v / rowsum(A)         (PV with fused softmax denominator)
// MODE 3: f32 out, + biasRow + Res(prefetched to regs), coalesced epilogue (final proj)
template<int MODE>
__device__ __forceinline__ void gemm_body(
    const unsigned short* __restrict__ A, const unsigned short* __restrict__ Bm,
    void* __restrict__ Cm, const float* __restrict__ biasRow,
    const float* __restrict__ biasCol, const float* __restrict__ Res,
    int K, int lda, int ldb, int ldc, float scale,
    long long sA, long long sB, long long sC, long long sRes) {
  // --- bijective XCD swizzle ---
  const int nbx = gridDim.x, nby = gridDim.y;
  const int nb = nbx * nby * gridDim.z;
  int lin = (blockIdx.z * nby + blockIdx.y) * nbx + blockIdx.x;
  int bx, by, bz;
  if ((nb & 7) == 0) {
    int logical = (lin & 7) * (nb >> 3) + (lin >> 3);
    bx = logical % nbx;
    int t = logical / nbx;
    by = t % nby;
    bz = t / nby;
  } else { bx = blockIdx.x; by = blockIdx.y; bz = blockIdx.z; }

  const unsigned short* Ab = A + (size_t)bz * sA;
  const unsigned short* Bb = Bm + (size_t)bz * sB;
  const int m0 = by * 128, n0 = bx * 128;
  __shared__ __align__(16) unsigned short sm[2][2][128 * 64];  // [A/B][dbuf][tile]
  const int tid = threadIdx.x, wave = tid >> 6, lane = tid & 63;
  const int wr = (wave >> 1) * 64, wc = (wave & 1) * 64;
  const int lr = lane & 15, lkc = lane >> 4;
  f32x4 acc[4][4] = {};
  f32x4 acc_d[4] = {};                               // MODE 2: row-sum
  s16x8 bones;
  #pragma unroll
  for (int j = 0; j < 8; ++j) bones[j] = (short)0x3F80;  // bf16 1.0

  // MODE 3: prefetch the residual tile into registers (read hides under the K-loop)
  float4 xr[16];
  if (MODE == 3) {
    #pragma unroll
    for (int pass = 0; pass < 2; ++pass)
      #pragma unroll
      for (int i = 0; i < 8; ++i) {
        int idx = i * 256 + tid;
        int rrow = idx >> 5, c4 = (idx & 31) << 2;
        size_t gidx = (size_t)(m0 + pass * 64 + rrow) * ldc + (n0 + c4);
        xr[pass * 8 + i] = *(const float4*)&Res[(size_t)bz * sRes + gidx];
      }
  }

  const int chunkBase = wave * 64 + lane;
  int srow[4], sc8[4];
  #pragma unroll
  for (int it = 0; it < 4; ++it) {
    int chunk = it * 256 + chunkBase;
    srow[it] = chunk >> 3;
    sc8[it] = (((chunk & 7) ^ (srow[it] & 7)) * 8);
  }

  #define STAGE(buf, kt)                                                                 \
    { _Pragma("unroll")                                                                  \
      for (int it = 0; it < 4; ++it) {                                                   \
        __builtin_amdgcn_global_load_lds(                                                \
            (const AS1 unsigned int*)(Ab + (size_t)(m0 + srow[it]) * lda + (kt) + sc8[it]), \
            (AS3 unsigned int*)(&sm[0][buf][0] + (size_t)(it * 256 + wave * 64) * 8), 16, 0, 0); \
        __builtin_amdgcn_global_load_lds(                                                \
            (const AS1 unsigned int*)(Bb + (size_t)(n0 + srow[it]) * ldb + (kt) + sc8[it]), \
            (AS3 unsigned int*)(&sm[1][buf][0] + (size_t)(it * 256 + wave * 64) * 8), 16, 0, 0); \
      }                                                                                  \
    }

  STAGE(0, 0);
  __syncthreads();
  int cur = 0;
  for (int kt = 0; kt < K; kt += 64) {
    if (kt + 64 < K) STAGE(cur ^ 1, kt + 64);
    #pragma unroll
    for (int kk = 0; kk < 64; kk += 32) {
      const int jbase = (kk >> 3) + lkc;
      s16x8 af[4], bfv[4];
      #pragma unroll
      for (int m = 0; m < 4; ++m) {
        int r = wr + m * 16 + lr;
        af[m] = *(const s16x8*)&sm[0][cur][r * 64 + ((jbase ^ (r & 7)) << 3)];
      }
      #pragma unroll
      for (int n = 0; n < 4; ++n) {
        int r = wc + n * 16 + lr;
        bfv[n] = *(const s16x8*)&sm[1][cur][r * 64 + ((jbase ^ (r & 7)) << 3)];
      }
      #pragma unroll
      for (int m = 0; m < 4; ++m) {
        #pragma unroll
        for (int n = 0; n < 4; ++n)
          acc[m][n] = __builtin_amdgcn_mfma_f32_16x16x32_bf16(af[m], bfv[n], acc[m][n], 0, 0, 0);
        if (MODE == 2)
          acc_d[m] = __builtin_amdgcn_mfma_f32_16x16x32_bf16(af[m], bones, acc_d[m], 0, 0, 0);
      }
    }
    __syncthreads();
    cur ^= 1;
  }
  #undef STAGE

  const int r0 = (lane >> 4) * 4, ccol = lane & 15;
  if (MODE == 0 && Res != nullptr && n0 >= 1024) {
    // ---- V-block: transpose tile via LDS bounce (pad 152 -> 2-way banks) -> vT (b,c,p) ----
    unsigned short* lt = (unsigned short*)&sm[0][0][0];   // [128][152] bf16 (38 KB)
    #pragma unroll
    for (int m = 0; m < 4; ++m) {
      const int gm_l = wr + m * 16 + r0;                  // local p-row (mult of 4)
      #pragma unroll
      for (int n = 0; n < 4; ++n) {
        const int gn_l = wc + n * 16 + ccol;              // local o-col
        const float bc = biasCol ? biasCol[n0 + gn_l] : 0.f;
        union { unsigned short us[4]; uint2 u2; } pk;
        #pragma unroll
        for (int r = 0; r < 4; ++r) pk.us[r] = f2bf(acc[m][n][r] + bc);
        *(uint2*)&lt[gn_l * 152 + gm_l] = pk.u2;          // transposed: [o][p]
      }
    }
    __syncthreads();
    unsigned short* vout = (unsigned short*)Res;          // vT base
    const int c0v = n0 - 1024;
    #pragma unroll
    for (int i = 0; i < 8; ++i) {
      int idx = i * 256 + tid;
      int orow = idx >> 4, pc = (idx & 15) * 8;
      s16x8 v = *(const s16x8*)&lt[orow * 152 + pc];
      *(s16x8*)&vout[(size_t)bz * sRes + (size_t)(c0v + orow) * HWP + m0 + pc] = v;
    }
  } else if (MODE != 3) {
    #pragma unroll
    for (int m = 0; m < 4; ++m) {
      const int gm = m0 + wr + m * 16 + r0;
      float inv[4] = {1.f, 1.f, 1.f, 1.f};
      if (MODE == 2) {
        inv[0] = 1.f / acc_d[m][0];
        inv[1] = 1.f / acc_d[m][1];
        inv[2] = 1.f / acc_d[m][2];
        inv[3] = 1.f / acc_d[m][3];
      }
      #pragma unroll
      for (int n = 0; n < 4; ++n) {
        const int gn = n0 + wc + n * 16 + ccol;
        const float bc = (MODE == 0 && biasCol) ? biasCol[gn] : 0.f;
        #pragma unroll
        for (int r = 0; r < 4; ++r) {
          float val = acc[m][n][r];
          if (MODE == 0) val = val * scale + bc;
          if (MODE == 2) val = val * inv[r];
          size_t idx = (size_t)(gm + r) * ldc + gn;
          ((unsigned short*)Cm)[(size_t)bz * sC + idx] = f2bf(val);
        }
      }
    }
  } else {
    // f32 out: coalesced epilogue via LDS bounce; residual already in xr registers
    float* ft = (float*)&sm[0][0][0];
    float* Cf = (float*)Cm;
    #pragma unroll
    for (int pass = 0; pass < 2; ++pass) {
      __syncthreads();
      if ((wave >> 1) == pass) {
        #pragma unroll
        for (int m = 0; m < 4; ++m) {
          const int rl0 = m * 16 + (lane >> 4) * 4;
          #pragma unroll
          for (int n = 0; n < 4; ++n) {
            const int cl = wc + n * 16 + (lane & 15);
            #pragma unroll
            for (int r = 0; r < 4; ++r) {
              float val = acc[m][n][r];
              if (biasRow) val += biasRow[m0 + pass * 64 + rl0 + r];
              ft[(rl0 + r) * 132 + cl] = val;
            }
          }
        }
      }
      __syncthreads();
      #pragma unroll
      for (int i = 0; i < 8; ++i) {
        int idx = i * 256 + tid;
        int rrow = idx >> 5, c4 = (idx & 31) << 2;
        float4 v = *(const float4*)&ft[rrow * 132 + c4];
        const float4 rv = xr[pass * 8 + i];
        v.x += rv.x; v.y += rv.y; v.z += rv.z; v.w += rv.w;
        size_t gidx = (size_t)(m0 + pass * 64 + rrow) * ldc + (n0 + c4);
        *(float4*)&Cf[(size_t)bz * sC + gidx] = v;
      }
    }
  }
}

#define GEMM_ARGS const unsigned short* A, const unsigned short* Bm, void* Cm,            \
                  const float* biasRow, const float* biasCol, const float* Res,            \
                  int K, int lda, int ldb, int ldc, float scale,                           \
                  long long sA, long long sB, long long sC, long long sRes
#define GEMM_PASS A, Bm, Cm, biasRow, biasCol, Res, K, lda, ldb, ldc, scale, sA, sB, sC, sRes

__global__ __launch_bounds__(256) void gemm_qkv(GEMM_ARGS) { gemm_body<0>(GEMM_PASS); }
__global__ __launch_bounds__(256) void gemm_pv(GEMM_ARGS)  { gemm_body<2>(GEMM_PASS); }
__global__ __launch_bounds__(256) void gemm_res(GEMM_ARGS) { gemm_body<3>(GEMM_PASS); }

// ================= S-GEMM: 256x128-tile, BK=32, dbuf, 8 waves, exp epilogue =================
// LDS = 2*(256*32 + 128*32)*2B = 48KB -> 3 blocks/CU. Staged bytes/elem 12B.
// Swizzle: 64B row stride -> f(r) = (r>>1)&3, applied at staging source AND ds_read.
__global__ __launch_bounds__(512)
void gemm_s256(const unsigned short* __restrict__ A, const unsigned short* __restrict__ Bm,
               unsigned short* __restrict__ C,
               int K, int lda, int ldb, int ldc, float scale,
               long long sA, long long sB, long long sC) {
  const int nbx = gridDim.x, nby = gridDim.y;
  const int nb = nbx * nby * gridDim.z;
  int lin = (blockIdx.z * nby + blockIdx.y) * nbx + blockIdx.x;
  int bx, by, bz;
  if ((nb & 7) == 0) {
    int logical = (lin & 7) * (nb >> 3) + (lin >> 3);
    bx = logical % nbx;
    int t = logical / nbx;
    by = t % nby;
    bz = t / nby;
  } else { bx = blockIdx.x; by = blockIdx.y; bz = blockIdx.z; }

  const unsigned short* __restrict__ Ab = A + (size_t)bz * sA;
  const unsigned short* __restrict__ Bb = Bm + (size_t)bz * sB;
  unsigned short* __restrict__ Cb = C + (size_t)bz * sC;
  const int m0 = by * 256, n0 = bx * 128;

  __shared__ __align__(16) unsigned short smA[2][256 * 32];
  __shared__ __align__(16) unsigned short smB[2][128 * 32];

  const int tid = threadIdx.x, wave = tid >> 6, lane = tid & 63;
  const int wr = (wave >> 1) * 64;
  const int wc = (wave & 1) * 64;
  const int lr = lane & 15, lkc = lane >> 4;
  f32x4 acc[4][4] = {};

  int aRow[2], aCol[2];
  #pragma unroll
  for (int it = 0; it < 2; ++it) {
    int chunk = it * 512 + tid;
    int row = chunk >> 2, cc = chunk & 3;
    aRow[it] = row;
    aCol[it] = ((cc ^ ((row >> 1) & 3)) * 8);
  }
  const int bRow = tid >> 2;
  const int bCol = (((tid & 3) ^ ((bRow >> 1) & 3)) * 8);

  #define STG_S(buf, kt)                                                                      \
    { _Pragma("unroll")                                                                       \
      for (int it = 0; it < 2; ++it)                                                          \
        __builtin_amdgcn_global_load_lds(                                                     \
            (const AS1 unsigned int*)(Ab + (size_t)(m0 + aRow[it]) * lda + (kt) + aCol[it]),  \
            (AS3 unsigned int*)(&smA[buf][0] + (size_t)(it * 512 + tid) * 8), 16, 0, 0);      \
      __builtin_amdgcn_global_load_lds(                                                       \
          (const AS1 unsigned int*)(Bb + (size_t)(n0 + bRow) * ldb + (kt) + bCol),            \
          (AS3 unsigned int*)(&smB[buf][0] + (size_t)tid * 8), 16, 0, 0);                     \
    }

  STG_S(0, 0);
  __syncthreads();
  int cur = 0;
  for (int kt = 0; kt < K; kt += 32) {
    if (kt + 32 < K) STG_S(cur ^ 1, kt + 32);
    s16x8 af[4], bfv[4];
    #pragma unroll
    for (int m = 0; m < 4; ++m) {
      int r = wr + m * 16 + lr;
      af[m] = *(const s16x8*)&smA[cur][r * 32 + ((lkc ^ ((r >> 1) & 3)) << 3)];
    }
    #pragma unroll
    for (int n = 0; n < 4; ++n) {
      int rb = wc + n * 16 + lr;
      bfv[n] = *(const s16x8*)&smB[cur][rb * 32 + ((lkc ^ ((rb >> 1) & 3)) << 3)];
    }
    #pragma unroll
    for (int m = 0; m < 4; ++m)
      #pragma unroll
      for (int n = 0; n < 4; ++n)
        acc[m][n] = __builtin_amdgcn_mfma_f32_16x16x32_bf16(af[m], bfv[n], acc[m][n], 0, 0, 0);
    __syncthreads();
    cur ^= 1;
  }
  #undef STG_S

  const int r0 = (lane >> 4) * 4, ccol = lane & 15;
  #pragma unroll
  for (int m = 0; m < 4; ++m) {
    const int gm = m0 + wr + m * 16 + r0;
    #pragma unroll
    for (int n = 0; n < 4; ++n) {
      const int gn = n0 + wc + n * 16 + ccol;
      #pragma unroll
      for (int r = 0; r < 4; ++r) {
        float val = __expf(acc[m][n][r] * scale);
        Cb[(size_t)(gm + r) * ldc + gn] = f2bf(val);
      }
    }
  }
}

extern "C" void kernel_launch(void* const* d_in, const int* in_sizes, int n_in,
                              void* d_out, int out_size, void* d_ws, size_t ws_size,
                              hipStream_t stream) {
  (void)in_sizes; (void)n_in; (void)out_size;
  const float* x   = (const float*)d_in[0];
  const float* nsc = (const float*)d_in[1];
  const float* nbi = (const float*)d_in[2];
  const float* wq  = (const float*)d_in[3];
  const float* bq  = (const float*)d_in[4];
  const float* wk  = (const float*)d_in[5];
  const float* bk  = (const float*)d_in[6];
  const float* wv  = (const float*)d_in[7];
  const float* bv  = (const float*)d_in[8];
  const float* wp  = (const float*)d_in[9];
  const float* bp  = (const float*)d_in[10];
  float* out = (float*)d_out;
  char* ws = (char*)d_ws;

  const size_t nW = (size_t)CCH * CCH;
  unsigned short* wb = (unsigned short*)ws;            // 2 MB
  float* bcat = (float*)(ws + 4 * nW * 2);             // 6 KB
  float* stats = bcat + 1536;                          // 2 KB
  const size_t o_h = 4 * nW * 2 + 16384;
  unsigned short* ht  = (unsigned short*)(ws + o_h);   // 32 MB  (b, p, 512)
  unsigned short* qkv = ht + (size_t)BATCH * HWP * CCH;        // 96 MB (b, p, 1536)
  unsigned short* vT  = qkv + (size_t)BATCH * HWP * 1536;      // 32 MB (b, c, p)
  unsigned short* Sb  = vT + (size_t)BATCH * CCH * HWP;        // G*32 MB slice (reused)
  unsigned short* ot  = ht;                            // alias: ht dead after QKV gemm
  const size_t o_S = o_h + ((size_t)BATCH * HWP * (CCH + 1536 + CCH)) * 2;
  const size_t sS1b = (size_t)HWP * HWP * 2;
  int G = 4;
  while (G > 1 && o_S + (size_t)G * sS1b > ws_size) G >>= 1;

  const long long sHC  = (long long)HWP * CCH;
  const long long sQKV = (long long)HWP * 1536;
  const long long sS1  = (long long)HWP * HWP;

  cvt_w<<<dim3((unsigned)((nW + 255) / 256)), dim3(256), 0, stream>>>(
      wq, wk, wv, wp, bq, bk, bv, wb, bcat);
  gn_stats<<<dim3(BATCH * NG), dim3(256), 0, stream>>>(x, stats);
  gn_apply<<<dim3(HWP / 64, CCH / 64, BATCH), dim3(256), 0, stream>>>(x, stats, nsc, nbi, ht);

  // fused QKV: qkv[p][o] = sum_c h_t[p][c] wqkv[o][c] + bcat[o];
  // V column-blocks (o>=1024) are written TRANSPOSED into vT (Res param = vT, sRes = sHC)
  gemm_qkv<<<dim3(1536 / 128, HWP / 128, BATCH), dim3(256), 0, stream>>>(
      ht, wb, qkv, nullptr, bcat, (const float*)vT,
      CCH, CCH, CCH, 1536, 1.f, sHC, 0, sQKV, sHC);

  const float sc = 0.04419417382415922f;               // 512^-0.5
  for (int b0 = 0; b0 < BATCH; b0 += G) {
    // expS[d][e] = exp(sc * sum_c q[d][c] k[e][c])   (fused exp; 256x128 BK=32 engine)
    gemm_s256<<<dim3(HWP / 128, HWP / 256, G), dim3(512), 0, stream>>>(
        qkv + (size_t)b0 * sQKV, qkv + 512 + (size_t)b0 * sQKV, Sb,
        CCH, 1536, 1536, HWP, sc, sQKV, sQKV, sS1);
    // o_t[d][c] = (sum_e expS[d][e] vT[c][e]) / (sum_e expS[d][e])   (fused denominator)
    gemm_pv<<<dim3(CCH / 128, HWP / 128, G), dim3(256), 0, stream>>>(
        Sb, vT + (size_t)b0 * sHC, ot + (size_t)b0 * sHC,
        nullptr, nullptr, nullptr,
        HWP, HWP, HWP, CCH, 1.f, sS1, sHC, sHC, 0);
  }

  // final: out[o][p] = x[o][p] + bp[o] + sum_c wp[o][c] o_t[p][c]   (f32, x prefetched)
  gemm_res<<<dim3(HWP / 128, CCH / 128, BATCH), dim3(256), 0, stream>>>(
      wb + 3 * nW, ot, out, bp, nullptr, x,
      CCH, CCH, CCH, HWP, 1.f, 0, sHC, sHC, sHC);
}